// Round 2
// baseline (886.202 us; speedup 1.0000x reference)
//
#include <hip/hip_runtime.h>
#include <stdint.h>

#define NB        16
#define IN_BITS   1024
#define N_IN      2048
#define N_ST      1024
#define N_OUT     512
#define TBL       65536
#define TBL_W     (TBL / 32)          // uint32 words per neuron bit-table
#define MAX_ITERS 4

// ---------------------------------------------------------------------------
// Binarize a float table into a packed bit table (bit j = src[j] > 0.5f).
// Each thread handles 4 consecutive floats (float4, coalesced 16 B/lane);
// nibbles are combined across the wave via shfl_xor; every 8th lane writes
// one uint32 covering 32 consecutive floats.
// ---------------------------------------------------------------------------
__global__ __launch_bounds__(256)
void binarize_kernel(const float4* __restrict__ src, uint32_t* __restrict__ dst) {
    const long t    = (long)blockIdx.x * blockDim.x + threadIdx.x;   // float4 index
    const int  lane = threadIdx.x & 63;

    float4 v = src[t];
    uint32_t p = (v.x > 0.5f ? 1u : 0u) | (v.y > 0.5f ? 2u : 0u) |
                 (v.z > 0.5f ? 4u : 0u) | (v.w > 0.5f ? 8u : 0u);
    p |= __shfl_xor(p, 1, 64) << 4;    // 8 bits on lanes 0 mod 2
    p |= __shfl_xor(p, 2, 64) << 8;    // 16 bits on lanes 0 mod 4
    p |= __shfl_xor(p, 4, 64) << 16;   // 32 bits on lanes 0 mod 8

    if ((lane & 7) == 0) {
        // wave base float4 = t - lane; 8 float4 = 1 uint32 word
        long word = (t - lane) / 8 + (lane >> 3);
        dst[word] = p;
    }
}

// ---------------------------------------------------------------------------
// Gather 16 bits from an LDS byte array via a 16-int connection row.
// ---------------------------------------------------------------------------
__device__ __forceinline__ int gather_addr(const uint8_t* sb, const int* __restrict__ c) {
    const int4* c4 = (const int4*)c;
    int4 a = c4[0], b = c4[1], cc = c4[2], d = c4[3];
    int addr = 0;
    addr |= (int)sb[a.x]  << 0;
    addr |= (int)sb[a.y]  << 1;
    addr |= (int)sb[a.z]  << 2;
    addr |= (int)sb[a.w]  << 3;
    addr |= (int)sb[b.x]  << 4;
    addr |= (int)sb[b.y]  << 5;
    addr |= (int)sb[b.z]  << 6;
    addr |= (int)sb[b.w]  << 7;
    addr |= (int)sb[cc.x] << 8;
    addr |= (int)sb[cc.y] << 9;
    addr |= (int)sb[cc.z] << 10;
    addr |= (int)sb[cc.w] << 11;
    addr |= (int)sb[d.x]  << 12;
    addr |= (int)sb[d.y]  << 13;
    addr |= (int)sb[d.z]  << 14;
    addr |= (int)sb[d.w]  << 15;
    return addr;
}

__device__ __forceinline__ uint8_t bit_lookup(const uint32_t* __restrict__ tbl,
                                              int neuron, int addr) {
    uint32_t w = tbl[(size_t)neuron * TBL_W + (addr >> 5)];
    return (uint8_t)((w >> (addr & 31)) & 1u);
}

// ---------------------------------------------------------------------------
// Main kernel: one block per batch element; all bit state in LDS.
// USE_BITS: in/state lookups hit the 24 MB packed bit tables (cache-resident)
// instead of the 768 MB float tables.
// ---------------------------------------------------------------------------
template <bool USE_BITS>
__global__ __launch_bounds__(1024)
void ram_multistep_kernel(const int*      __restrict__ x,
                          const int*      __restrict__ conn_in,
                          const int*      __restrict__ conn_state,
                          const int*      __restrict__ conn_out,
                          const float*    __restrict__ mem_in,
                          const float*    __restrict__ mem_state,
                          const float*    __restrict__ mem_out,
                          const uint32_t* __restrict__ inbits,
                          const uint32_t* __restrict__ stbits,
                          float*          __restrict__ out)
{
    __shared__ uint8_t xb[IN_BITS];
    __shared__ uint8_t bits[N_IN + N_ST];   // [0,2048) in_bits, [2048,3072) state_bits

    const int b   = blockIdx.x;
    const int tid = threadIdx.x;

    if (tid < IN_BITS) xb[tid] = (uint8_t)x[b * IN_BITS + tid];
    if (tid < N_ST)    bits[N_IN + tid] = 0;
    __syncthreads();

    // Phase 1: in-layer (2048 neurons, 2 per thread).
    #pragma unroll
    for (int n = tid; n < N_IN; n += 1024) {
        int addr = gather_addr(xb, conn_in + n * NB);
        uint8_t bit;
        if (USE_BITS) {
            bit = bit_lookup(inbits, n, addr);
        } else {
            bit = (mem_in[(size_t)n * TBL + (size_t)addr] > 0.5f) ? 1 : 0;
        }
        bits[n] = bit;
    }
    __syncthreads();

    // Phase 2: 4 state iterations (1024 neurons, 1 per thread).
    for (int it = 0; it < MAX_ITERS; ++it) {
        uint8_t nbit = 0;
        if (tid < N_ST) {
            int addr = gather_addr(bits, conn_state + tid * NB);
            if (USE_BITS) {
                nbit = bit_lookup(stbits, tid, addr);
            } else {
                nbit = (mem_state[(size_t)tid * TBL + (size_t)addr] > 0.5f) ? 1 : 0;
            }
        }
        __syncthreads();
        if (tid < N_ST) bits[N_IN + tid] = nbit;
        __syncthreads();
    }

    // Phase 3: out lookups (only the final iteration's out_vals survive).
    if (tid < N_OUT) {
        int addr = gather_addr(bits, conn_out + tid * NB);
        out[b * N_OUT + tid] = mem_out[(size_t)tid * TBL + (size_t)addr];
    }
}

extern "C" void kernel_launch(void* const* d_in, const int* in_sizes, int n_in,
                              void* d_out, int out_size, void* d_ws, size_t ws_size,
                              hipStream_t stream) {
    const int*   x          = (const int*)  d_in[0];
    const int*   conn_in    = (const int*)  d_in[1];
    const int*   conn_state = (const int*)  d_in[2];
    const int*   conn_out   = (const int*)  d_in[3];
    const float* mem_in     = (const float*)d_in[4];
    const float* mem_state  = (const float*)d_in[5];
    const float* mem_out    = (const float*)d_in[6];
    float*       out        = (float*)d_out;

    const int B = in_sizes[0] / IN_BITS;   // 256

    const size_t in_words = (size_t)N_IN * TBL_W;   // 4 M words = 16 MB
    const size_t st_words = (size_t)N_ST * TBL_W;   // 2 M words =  8 MB
    const size_t need     = (in_words + st_words) * sizeof(uint32_t);

    if (ws_size >= need) {
        uint32_t* inbits = (uint32_t*)d_ws;
        uint32_t* stbits = inbits + in_words;

        // mem_in: 2048*65536 floats / 4 / 256 = 131072 blocks
        hipLaunchKernelGGL(binarize_kernel, dim3((N_IN * (TBL / 4)) / 256), dim3(256),
                           0, stream, (const float4*)mem_in, inbits);
        // mem_state: 1024*65536 floats / 4 / 256 = 65536 blocks
        hipLaunchKernelGGL(binarize_kernel, dim3((N_ST * (TBL / 4)) / 256), dim3(256),
                           0, stream, (const float4*)mem_state, stbits);

        hipLaunchKernelGGL(ram_multistep_kernel<true>, dim3(B), dim3(1024), 0, stream,
                           x, conn_in, conn_state, conn_out,
                           mem_in, mem_state, mem_out, inbits, stbits, out);
    } else {
        hipLaunchKernelGGL(ram_multistep_kernel<false>, dim3(B), dim3(1024), 0, stream,
                           x, conn_in, conn_state, conn_out,
                           mem_in, mem_state, mem_out,
                           (const uint32_t*)nullptr, (const uint32_t*)nullptr, out);
    }
}